// Round 14
// baseline (687.213 us; speedup 1.0000x reference)
//
#include <hip/hip_runtime.h>
#include <stdint.h>

// HamiltonianFlow: x [256, 8, 32, 2] (q,p); H = 0.5*sum(p^2) + MLP(q).
// dq/dt = p, dp/dt = -W1 @ [(1-tanh(z)^2) * W2], z = q^T W1 + b1.
// 100 RK4 steps = 400 sequential stages (fwd+bwd matvec each).
//
// R14: FEWER, FATTER WAVES. R10-R13 all measured ~2300 cyc/stage with MFMA
// issue at its 1033-cyc floor while busy (MfmaUtil ~50%): waves are LOCKSTEP
// (shared barrier), so extra waves don't stagger the ~1200-cyc serial tail
// -- they only multiply LDS broadcast reads (16 waves x 16 b128/stage) and
// barrier cost. So: 4 waves (1/SIMD), wave owns 4 tiles (comps 64w+16i+s):
//  - 64 bcast reads/stage/CU (4x fewer), each batch of 8 feeds 32 MFMAs
//  - 8 indep accumulator chains/wave -> one wave saturates SIMD MFMA issue
//  - barrier resyncs 4 waves, not 16
//  - 1 wave/SIMD = 512-reg budget: 256 weight regs + 64 batched A-operands
//    stay architectural VGPRs (no AGPR copies, no LDS remat).
// Single-phase pipeline unchanged from R12/R13 (passed 1.95e-3): per stage
// VALU top (u=act(z), RK4 with g_{s-1}, q_{s+1}), masked b16 writes, ONE
// barrier, merged MFMA: g_s = W u_s AND z_{s+1} = W^T q_{s+1} + b1.
//   fwd B-frag wF[i][kk][j]  = W[32kk+8quad+j][c_i]  (column gather, once)
//   bwd B-frag wBt[i][kk][j] = W[c_i][32kk+8quad+j]  (contiguous b128, once)
// A = vector replicated over rows, wave-uniform-per-quad b128 bcast reads.
// Double-buffered qsh/ush (buf=it&1). FULL unroll on every reg-array access
// (R4: any dynamic index => scratch spill).
// Numerics: f16 storage, fp32 MFMA accumulate (R3/5/7/8/10/12/13 class).

typedef _Float16 v8h __attribute__((ext_vector_type(8)));
typedef _Float16 v4h __attribute__((ext_vector_type(4)));
typedef float v4f __attribute__((ext_vector_type(4)));

#define NSTEPS 100
#define WS 264   // padded f16 row stride (528 B: rows 16B-aligned, bank shift)

__global__ __launch_bounds__(256, 1)
void ham_kernel(const float* __restrict__ x0, const float* __restrict__ W1,
                const float* __restrict__ b1, const float* __restrict__ W2,
                float* __restrict__ out)
{
    __shared__ __align__(16) _Float16 wlds[256 * WS];   // 135168 B staged W1
    __shared__ __align__(16) _Float16 qsh[2][256];      // double-buffered
    __shared__ __align__(16) _Float16 ush[2][256];

    const int t = threadIdx.x;
    const int w = t >> 6;          // wave 0..3: owns tiles 4w..4w+3
    const int l = t & 63;
    const int quad = l >> 4;       // K-subgroup
    const int s = l & 15;          // owned column
    const int blk = blockIdx.x;

    // ---- stage W1 -> LDS f16 (padded rows), coalesced ----
    #pragma unroll 1
    for (int k = t; k < 65536 / 4; k += 256) {
        const int row = k >> 6, col4 = (k & 63) * 4;
        float4 v = ((const float4*)W1)[k];
        v4h h; h[0] = (_Float16)v.x; h[1] = (_Float16)v.y;
               h[2] = (_Float16)v.z; h[3] = (_Float16)v.w;
        *(v4h*)(wlds + row * WS + col4) = h;
    }
    __syncthreads();

    // ---- weight B-frags: 4 tiles x 8 kk x 2 orientations, FULL unroll ----
    v8h wF[4][8], wBt[4][8];
    #pragma unroll
    for (int i = 0; i < 4; ++i) {
        const int ci = 64 * w + 16 * i + s;
        #pragma unroll
        for (int kk = 0; kk < 8; ++kk) {
            wBt[i][kk] = *(const v8h*)(wlds + ci * WS + 32 * kk + 8 * quad);
            #pragma unroll
            for (int j = 0; j < 8; ++j)
                wF[i][kk][j] = wlds[(32 * kk + 8 * quad + j) * WS + ci];
        }
    }

    // ---- per-comp state (4 owned comps/lane, dup across quads) ----
    float b1r[4], w2r[4], q0[4], p0[4], z[4], g[4], accq[4], accp[4];
    #pragma unroll
    for (int i = 0; i < 4; ++i) {
        const int ci = 64 * w + 16 * i + s;
        b1r[i] = b1[ci];
        w2r[i] = W2[ci];
        float2 qp = ((const float2*)(x0 + (size_t)blk * 512))[ci];
        q0[i] = qp.x; p0[i] = qp.y;
        if (quad == 0) qsh[1][ci] = (_Float16)q0[i];
        g[i] = 0.f; accq[i] = 0.f; accp[i] = 0.f;
    }
    __syncthreads();

    const float dt = 0.01f, hdt = 0.005f, dt6 = 0.01f / 6.f;

    // ---- prologue: z_1 = W^T q0 + b1 (buffer 1) ----
    {
        v8h aq[8];
        #pragma unroll
        for (int kk = 0; kk < 8; ++kk)
            aq[kk] = *(const v8h*)(&qsh[1][0] + 32 * kk + 8 * quad);
        v4f C[4];
        #pragma unroll
        for (int i = 0; i < 4; ++i) C[i] = (v4f){b1r[i], b1r[i], b1r[i], b1r[i]};
        #pragma unroll
        for (int kk = 0; kk < 8; ++kk)
            #pragma unroll
            for (int i = 0; i < 4; ++i)
                C[i] = __builtin_amdgcn_mfma_f32_16x16x32_f16(
                           aq[kk], wF[i][kk], C[i], 0, 0, 0);
        #pragma unroll
        for (int i = 0; i < 4; ++i) z[i] = C[i][0];
    }

    #pragma unroll 1
    for (int it = 0; it < NSTEPS * 4; ++it) {
        const int stg = it & 3;
        const int buf = it & 1;

        // ---- u_s = act(z_s); RK4 with g_{s-1}; q_{s+1}; writes ----
        #pragma unroll
        for (int i = 0; i < 4; ++i) {
            float e = __expf(2.f * z[i]);         // tanh via exp; saturates ok
            float hh = 1.f - 2.f / (e + 1.f);
            float u = (1.f - hh * hh) * w2r[i];

            float kq, qnext;
            if (stg == 0) {
                if (it) { accp[i] -= g[i]; p0[i] += dt6 * accp[i]; }
                kq = p0[i]; accq[i] = kq;
                qnext = q0[i] + hdt * kq;
            } else if (stg == 1) {
                accp[i] = -g[i];
                kq = p0[i] - hdt * g[i];
                accq[i] += 2.f * kq;
                qnext = q0[i] + hdt * kq;
            } else if (stg == 2) {
                accp[i] -= 2.f * g[i];
                kq = p0[i] - hdt * g[i];
                accq[i] += 2.f * kq;
                qnext = q0[i] + dt * kq;
            } else {
                accp[i] -= 2.f * g[i];
                kq = p0[i] - dt * g[i];
                accq[i] += kq;
                q0[i] += dt6 * accq[i];
                qnext = q0[i];
            }
            if (quad == 0) {
                const int ci = 64 * w + 16 * i + s;
                ush[buf][ci] = (_Float16)u;
                qsh[buf][ci] = (_Float16)qnext;
            }
        }
        __syncthreads();

        // ---- batched A-operand reads (64 VGPRs), then merged MFMA ----
        v8h au[8], aq[8];
        #pragma unroll
        for (int kk = 0; kk < 8; ++kk) {
            au[kk] = *(const v8h*)(&ush[buf][0] + 32 * kk + 8 * quad);
            aq[kk] = *(const v8h*)(&qsh[buf][0] + 32 * kk + 8 * quad);
        }
        v4f G[4], C[4];
        #pragma unroll
        for (int i = 0; i < 4; ++i) {
            G[i] = (v4f){0.f, 0.f, 0.f, 0.f};
            C[i] = (v4f){b1r[i], b1r[i], b1r[i], b1r[i]};
        }
        #pragma unroll
        for (int kk = 0; kk < 8; ++kk) {
            #pragma unroll
            for (int i = 0; i < 4; ++i) {
                G[i] = __builtin_amdgcn_mfma_f32_16x16x32_f16(
                           au[kk], wBt[i][kk], G[i], 0, 0, 0);
                C[i] = __builtin_amdgcn_mfma_f32_16x16x32_f16(
                           aq[kk], wF[i][kk], C[i], 0, 0, 0);
            }
        }
        #pragma unroll
        for (int i = 0; i < 4; ++i) { g[i] = G[i][0]; z[i] = C[i][0]; }
    }

    // ---- epilogue: finish p with g_4 of the last step; store ----
    #pragma unroll
    for (int i = 0; i < 4; ++i) {
        accp[i] -= g[i];
        p0[i] += dt6 * accp[i];
        if (quad == 0) {
            const int ci = 64 * w + 16 * i + s;
            ((float2*)(out + (size_t)blk * 512))[ci] = make_float2(q0[i], p0[i]);
        }
    }
}

extern "C" void kernel_launch(void* const* d_in, const int* in_sizes, int n_in,
                              void* d_out, int out_size, void* d_ws, size_t ws_size,
                              hipStream_t stream) {
    const float* x0 = (const float*)d_in[0];
    const float* W1 = (const float*)d_in[1];
    const float* b1 = (const float*)d_in[2];
    const float* W2 = (const float*)d_in[3];
    // d_in[4] = b2: constant offset, no effect on the gradient/dynamics.
    float* out = (float*)d_out;
    hipLaunchKernelGGL(ham_kernel, dim3(256), dim3(256), 0, stream,
                       x0, W1, b1, W2, out);
}

// Round 15
// 348.813 us; speedup vs baseline: 1.9701x; 1.9701x over previous
//
#include <hip/hip_runtime.h>
#include <stdint.h>

// HamiltonianFlow: x [256, 8, 32, 2] (q,p); H = 0.5*sum(p^2) + MLP(q).
// dq/dt = p, dp/dt = -g, g = W*u(z), z = W^T q + b1, u = (1-tanh^2(z)).*W2.
// 100 RK4 steps. R10-R14 plateaued at ~378us: 2 matvecs/stage, MFMA pipe at
// floor when busy, ~1030 cyc/stage exposed tail. R15 halves the matvec count
// ALGEBRAICALLY: iterate in z-space with M = W^T W (precomputed per block).
//   z1'= z1 + dt*P - dt*dt6*(Y1+Y2+Y3),  P' = P - dt6*(Y1+2Y2+2Y3+Y4),
//   z2 = z1+hdt*P, z3 = z1+hdt*P-hdt^2*Y1, z4 = z1+dt*P-dt*hdt*Y2,
//   Y_i = M u_i  <-- the ONLY per-stage matvec (was 2: W^T q and W u).
// q,p reconstructed at the end from in-lane u-accumulators:
//   S1 = sum_n s_p^(n),  S23 = sum_n (99-n)*s_p^(n) + sum_n s_q^(n),
//   s_p = u1+2u2+2u3+u4, s_q = u1+u2+u3,
//   p_T = p0 - dt6*W*S1,  q_T = q0 + dt*100*p0 - dt*dt6*W*S23.
// M build: per wave, 16 tiles M[16kb:+16][16w:+16] via MFMA (A,B = wF-style
// frags from resident W-LDS); D redistributed to B-frag layout via per-wave
// scratch (tile kb serves quads 2(kb&1),2(kb&1)+1; rit=8*(q&1)+j).
// Loop: 16 waves (4/SIMD), wave w owns comps [16w,16w+16) (quads dup),
// single barrier/stage, u double-buffered, Y = C[0] (column-owned).
// FULL unroll on every reg-array access (R4: dynamic index => scratch).
// Numerics: f16 storage (W, M, u, S), fp32 MFMA accumulate + fp32 z1/P state.

typedef _Float16 v8h __attribute__((ext_vector_type(8)));
typedef _Float16 v4h __attribute__((ext_vector_type(4)));
typedef float v4f __attribute__((ext_vector_type(4)));

#define NSTEPS 100
#define WS 264   // padded f16 row stride (528 B: rows 16B-aligned)

__global__ __launch_bounds__(1024, 4)
void ham_kernel(const float* __restrict__ x0, const float* __restrict__ W1,
                const float* __restrict__ b1, const float* __restrict__ W2,
                float* __restrict__ out)
{
    __shared__ __align__(16) _Float16 wlds[256 * WS];   // 135168 B: W (f16)
    __shared__ __align__(16) float    mscr[16 * 256];   // 16 KB: per-wave M scratch
    __shared__ __align__(16) _Float16 ubuf[2][256];     // u broadcast, dbuf

    const int t = threadIdx.x;
    const int w = t >> 6;          // wave 0..15: owns comps [16w, 16w+16)
    const int l = t & 63;
    const int quad = l >> 4;       // K-subgroup
    const int s = l & 15;          // owned column
    const int comp = 16 * w + s;
    const int blk = blockIdx.x;

    // ---- stage W1 -> LDS f16 (padded rows), coalesced ----
    #pragma unroll 1
    for (int k = t; k < 65536 / 4; k += 1024) {
        const int row = k >> 6, col4 = (k & 63) * 4;
        float4 v = ((const float4*)W1)[k];
        v4h h; h[0] = (_Float16)v.x; h[1] = (_Float16)v.y;
               h[2] = (_Float16)v.z; h[3] = (_Float16)v.w;
        *(v4h*)(wlds + row * WS + col4) = h;
    }
    __syncthreads();

    // ---- wF: own-column W^T frag (B-op): wF[kk][j] = W[32kk+8quad+j][comp]
    v8h wF[8];
    #pragma unroll
    for (int kk = 0; kk < 8; ++kk)
        #pragma unroll
        for (int j = 0; j < 8; ++j)
            wF[kk][j] = wlds[(32 * kk + 8 * quad + j) * WS + comp];

    // ---- build M = W^T W column-block frags wM (B-op: M[k][comp]) ----
    // tile kb: D[m][n] = sum_k W[k][16kb+m] * W[k][16w+n] = M[16kb+m][16w+n]
    v8h wM[8];
    float* scr = mscr + w * 256;
    #pragma unroll
    for (int kb = 0; kb < 16; ++kb) {
        v8h aM[8];   // A[m=s][k=8quad+j] = W[32kk+8quad+j][16kb+s]
        #pragma unroll
        for (int kk = 0; kk < 8; ++kk)
            #pragma unroll
            for (int j = 0; j < 8; ++j)
                aM[kk][j] = wlds[(32 * kk + 8 * quad + j) * WS + 16 * kb + s];
        v4f D = {0.f, 0.f, 0.f, 0.f};
        #pragma unroll
        for (int kk = 0; kk < 8; ++kk)
            D = __builtin_amdgcn_mfma_f32_16x16x32_f16(aM[kk], wF[kk], D, 0, 0, 0);
        // scratch[s*16 + (4quad+r)] = M[16kb + 4quad+r][16w+s]
        *(v4f*)(scr + s * 16 + 4 * quad) = D;
        asm volatile("s_waitcnt lgkmcnt(0)" ::: "memory");  // in-wave cross-lane
        // tile kb serves quads {2(kb&1), 2(kb&1)+1}: rit = 8*(quad&1)+j
        if ((quad >> 1) == (kb & 1)) {
            #pragma unroll
            for (int j = 0; j < 8; ++j)
                wM[kb >> 1][j] = (_Float16)scr[s * 16 + 8 * (quad & 1) + j];
        }
        asm volatile("s_waitcnt lgkmcnt(0)" ::: "memory");
    }

    const float b1r = b1[comp];
    const float w2r = W2[comp];
    float2 qp = ((const float2*)(x0 + (size_t)blk * 512))[comp];
    const float q0o = qp.x, p0o = qp.y;

    // ---- prologue: z1 = W^T q0 + b1, P = W^T p0 ----
    if (quad == 0) { ubuf[0][comp] = (_Float16)q0o; ubuf[1][comp] = (_Float16)p0o; }
    __syncthreads();
    float z1, P;
    {
        v4f Cq = {b1r, b1r, b1r, b1r}, Cp = {0.f, 0.f, 0.f, 0.f};
        const _Float16* qb = &ubuf[0][0] + 8 * quad;
        const _Float16* pb = &ubuf[1][0] + 8 * quad;
        #pragma unroll
        for (int kk = 0; kk < 8; ++kk) {
            v8h aq = *(const v8h*)(qb + 32 * kk);
            v8h ap = *(const v8h*)(pb + 32 * kk);
            Cq = __builtin_amdgcn_mfma_f32_16x16x32_f16(aq, wF[kk], Cq, 0, 0, 0);
            Cp = __builtin_amdgcn_mfma_f32_16x16x32_f16(ap, wF[kk], Cp, 0, 0, 0);
        }
        z1 = Cq[0]; P = Cp[0];
    }
    __syncthreads();   // protect ubuf before loop overwrites

    const float dt = 0.01f, hdt = 0.005f, dt6 = 0.01f / 6.f;
    const float dtdt6 = dt * dt6, hdt2 = hdt * hdt, dthdt = dt * hdt;

    float Y = 0.f, Y1v = 0.f, Y2v = 0.f, Yq = 0.f, Yp = 0.f;
    float up = 0.f, uq = 0.f, S1 = 0.f, S23 = 0.f, cn = 99.f;

    #pragma unroll 1
    for (int it = 0; it < NSTEPS * 4; ++it) {
        const int stg = it & 3;
        const int buf = it & 1;

        // ---- z for this stage from (z1, P, Y-history) ----
        float z;
        if (stg == 0) {
            if (it) {
                Yp += Y;                       // + Y4
                z1 = z1 + dt * P - dtdt6 * Yq; // uses pre-update P
                P  = P - dt6 * Yp;
                S1 += up; S23 += cn * up + uq; cn -= 1.f;
            }
            z = z1;
        } else if (stg == 1) {
            Y1v = Y; Yq = Y; Yp = Y;
            z = z1 + hdt * P;
        } else if (stg == 2) {
            Y2v = Y; Yq += Y; Yp += 2.f * Y;
            z = z1 + hdt * P - hdt2 * Y1v;
        } else {
            Yq += Y; Yp += 2.f * Y;
            z = z1 + dt * P - dthdt * Y2v;
        }

        // ---- u = (1 - tanh^2(z)) * W2 ----
        float e = __expf(2.f * z);
        float hh = 1.f - 2.f / (e + 1.f);
        float u = (1.f - hh * hh) * w2r;
        if (stg == 0)      { up = u;          uq = u;  }
        else if (stg == 3) { up += u;                  }
        else               { up += 2.f * u;   uq += u; }

        if (quad == 0) ubuf[buf][comp] = (_Float16)u;
        __syncthreads();

        // ---- Y = M u (column-owned: Y = C[0]) ----
        const _Float16* ub = &ubuf[buf][0] + 8 * quad;
        v4f Ca = {0.f, 0.f, 0.f, 0.f}, Cb = {0.f, 0.f, 0.f, 0.f};
        #pragma unroll
        for (int kk = 0; kk < 8; kk += 2) {
            v8h a0 = *(const v8h*)(ub + 32 * kk);
            v8h a1 = *(const v8h*)(ub + 32 * (kk + 1));
            Ca = __builtin_amdgcn_mfma_f32_16x16x32_f16(a0, wM[kk], Ca, 0, 0, 0);
            Cb = __builtin_amdgcn_mfma_f32_16x16x32_f16(a1, wM[kk + 1], Cb, 0, 0, 0);
        }
        Y = Ca[0] + Cb[0];
    }
    S1 += up; S23 += uq;   // last step: cn == 0

    // ---- epilogue: p_T = p0 - dt6*W*S1; q_T = q0 + dt*100*p0 - dt*dt6*W*S23
    if (quad == 0) { ubuf[0][comp] = (_Float16)S1; ubuf[1][comp] = (_Float16)S23; }
    __syncthreads();
    v8h wBt[8];   // B-op: W[comp][32kk+8quad+j] (contiguous b128)
    #pragma unroll
    for (int kk = 0; kk < 8; ++kk)
        wBt[kk] = *(const v8h*)(wlds + comp * WS + 32 * kk + 8 * quad);
    v4f D1 = {0.f, 0.f, 0.f, 0.f}, D2 = {0.f, 0.f, 0.f, 0.f};
    {
        const _Float16* s1b = &ubuf[0][0] + 8 * quad;
        const _Float16* s2b = &ubuf[1][0] + 8 * quad;
        #pragma unroll
        for (int kk = 0; kk < 8; ++kk) {
            v8h a1 = *(const v8h*)(s1b + 32 * kk);
            v8h a2 = *(const v8h*)(s2b + 32 * kk);
            D1 = __builtin_amdgcn_mfma_f32_16x16x32_f16(a1, wBt[kk], D1, 0, 0, 0);
            D2 = __builtin_amdgcn_mfma_f32_16x16x32_f16(a2, wBt[kk], D2, 0, 0, 0);
        }
    }
    float pT = p0o - dt6 * D1[0];
    float qT = q0o + dt * (float)NSTEPS * p0o - dtdt6 * D2[0];

    if (quad == 0)
        ((float2*)(out + (size_t)blk * 512))[comp] = make_float2(qT, pT);
}

extern "C" void kernel_launch(void* const* d_in, const int* in_sizes, int n_in,
                              void* d_out, int out_size, void* d_ws, size_t ws_size,
                              hipStream_t stream) {
    const float* x0 = (const float*)d_in[0];
    const float* W1 = (const float*)d_in[1];
    const float* b1 = (const float*)d_in[2];
    const float* W2 = (const float*)d_in[3];
    // d_in[4] = b2: constant offset, no effect on the gradient/dynamics.
    float* out = (float*)d_out;
    hipLaunchKernelGGL(ham_kernel, dim3(256), dim3(1024), 0, stream,
                       x0, W1, b1, W2, out);
}

// Round 16
// 280.052 us; speedup vs baseline: 2.4539x; 1.2455x over previous
//
#include <hip/hip_runtime.h>
#include <stdint.h>

// HamiltonianFlow: x [256, 8, 32, 2] (q,p); H = 0.5*sum(p^2) + MLP(q).
// dq/dt = p, dp/dt = -W u(z), z = W^T q + b1, u = (1-tanh^2(z)).*W2.
// 100 RK4 steps, z-space iteration with M = W^T W (R15-verified algebra):
//   z2 = z1+hdt*P            (NO matvec needed!)
//   z3 = z1+hdt*P-hdt^2*Y1,  z4 = z1+dt*P-dt*hdt*Y2,   Y_i = M u_i
//   z1' = z1+dt*P-dt*dt6*(Y1+Y2+Y3),  P' = P-dt6*(Y1+2Y2+2Y3+Y4)
// R16: since u1,u2 need no Y, and u3,u4 need only Y1,Y2:
//   phase A: u1,u2 -> barrier -> {Y1,Y2} merged MFMA
//   phase B: u3,u4 -> barrier -> {Y3,Y4} merged MFMA
// = TWO barriers/step (structural minimum), 200 phases vs R15's 400.
// Fixed per-phase costs (read latency, tanh, drain, barrier resync) now
// amortize over 2 matvecs; 4 indep accumulator chains per phase.
// + R13 asm trick: v_mfma with "a" constraint reads wM DIRECTLY from AGPRs
//   (R15's builtin forced v_accvgpr_read copies: ~260 cyc/stage of VALUBusy).
// + M-build scratch stride 20 floats (16B-aligned v4f, 2-way conflicts=free;
//   R15's stride 16 was 8-way -> 1.3e7 conflicts).
// Reconstruction (R15-verified): S1 = sum sp_n, S23 = sum (99-n)sp_n + sq_n,
//   sp = u1+2u2+2u3+u4, sq = u1+u2+u3;
//   p_T = p0 - dt6*W*S1, q_T = q0 + dt*100*p0 - dt*dt6*W*S23.
// 16 waves (4/SIMD), wave w owns comps [16w,16w+16) (quads dup, comp=16w+s).
// Buffer safety: phase-A MFMA reads of step n complete before that wave
// reaches barrier B (data dependency), so ubuf[0,1] rewrite at step n+1
// (after barrier B) is race-free; same for ubuf[2,3] after barrier A.
// FULL unroll on every reg-array access (R4: dynamic index => scratch).
// Numerics: f16 storage (W, M, u, S), fp32 MFMA accum + fp32 z1/P state.

typedef _Float16 v8h __attribute__((ext_vector_type(8)));
typedef _Float16 v4h __attribute__((ext_vector_type(4)));
typedef float v4f __attribute__((ext_vector_type(4)));

#define NSTEPS 100
#define WS 264   // padded f16 row stride (528 B: rows 16B-aligned)

// D(+=C) in VGPRs, A (broadcast vector) in VGPRs, B (M-frag) read from AGPRs.
#define MFMA_AV(C, A, B) \
    asm("v_mfma_f32_16x16x32_f16 %0, %1, %2, %0" : "+v"(C) : "v"(A), "a"(B))

__global__ __launch_bounds__(1024, 4)
void ham_kernel(const float* __restrict__ x0, const float* __restrict__ W1,
                const float* __restrict__ b1, const float* __restrict__ W2,
                float* __restrict__ out)
{
    __shared__ __align__(16) _Float16 wlds[256 * WS];   // 135168 B: W (f16)
    __shared__ __align__(16) float    mscr[16 * 320];   // 20480 B: M scratch, stride 20
    __shared__ __align__(16) _Float16 ubuf[4][256];     // u1,u2,u3,u4 bcast

    const int t = threadIdx.x;
    const int w = t >> 6;          // wave 0..15: owns comps [16w, 16w+16)
    const int l = t & 63;
    const int quad = l >> 4;       // K-subgroup
    const int s = l & 15;          // owned column
    const int comp = 16 * w + s;
    const int blk = blockIdx.x;

    // ---- stage W1 -> LDS f16 (padded rows), coalesced ----
    #pragma unroll 1
    for (int k = t; k < 65536 / 4; k += 1024) {
        const int row = k >> 6, col4 = (k & 63) * 4;
        float4 v = ((const float4*)W1)[k];
        v4h h; h[0] = (_Float16)v.x; h[1] = (_Float16)v.y;
               h[2] = (_Float16)v.z; h[3] = (_Float16)v.w;
        *(v4h*)(wlds + row * WS + col4) = h;
    }
    __syncthreads();

    // ---- wF: own-column W^T frag (B-op): wF[kk][j] = W[32kk+8quad+j][comp]
    v8h wF[8];
    #pragma unroll
    for (int kk = 0; kk < 8; ++kk)
        #pragma unroll
        for (int j = 0; j < 8; ++j)
            wF[kk][j] = wlds[(32 * kk + 8 * quad + j) * WS + comp];

    // ---- build M = W^T W column-block frags wM (B-op: M[k][comp]) ----
    // tile kb: D[m][n] = M[16kb+m][16w+n]; scr stride 20 (16B-aligned v4f,
    // banks 20s%32 period-8 => 2-way, free). tile kb serves quads with
    // quad>>1 == kb&1; local row = 8*(quad&1)+j; kk2 = kb>>1.
    v8h wM[8];
    float* scr = mscr + w * 320;
    #pragma unroll
    for (int kb = 0; kb < 16; ++kb) {
        v8h aM[8];   // A[m=s][k=8quad+j] = W[32kk+8quad+j][16kb+s]
        #pragma unroll
        for (int kk = 0; kk < 8; ++kk)
            #pragma unroll
            for (int j = 0; j < 8; ++j)
                aM[kk][j] = wlds[(32 * kk + 8 * quad + j) * WS + 16 * kb + s];
        v4f D = {0.f, 0.f, 0.f, 0.f};
        #pragma unroll
        for (int kk = 0; kk < 8; ++kk)
            D = __builtin_amdgcn_mfma_f32_16x16x32_f16(aM[kk], wF[kk], D, 0, 0, 0);
        *(v4f*)(scr + s * 20 + 4 * quad) = D;
        asm volatile("s_waitcnt lgkmcnt(0)" ::: "memory");  // in-wave cross-lane
        if ((quad >> 1) == (kb & 1)) {
            #pragma unroll
            for (int j = 0; j < 8; ++j)
                wM[kb >> 1][j] = (_Float16)scr[s * 20 + 8 * (quad & 1) + j];
        }
        asm volatile("s_waitcnt lgkmcnt(0)" ::: "memory");
    }

    const float b1r = b1[comp];
    const float w2r = W2[comp];
    float2 qp = ((const float2*)(x0 + (size_t)blk * 512))[comp];
    const float q0o = qp.x, p0o = qp.y;

    // ---- prologue: z1 = W^T q0 + b1, P = W^T p0 ----
    if (quad == 0) { ubuf[0][comp] = (_Float16)q0o; ubuf[1][comp] = (_Float16)p0o; }
    __syncthreads();
    float z1, P;
    {
        v4f Cq = {b1r, b1r, b1r, b1r}, Cp = {0.f, 0.f, 0.f, 0.f};
        const _Float16* qb = &ubuf[0][0] + 8 * quad;
        const _Float16* pb = &ubuf[1][0] + 8 * quad;
        #pragma unroll
        for (int kk = 0; kk < 8; ++kk) {
            v8h aq = *(const v8h*)(qb + 32 * kk);
            v8h ap = *(const v8h*)(pb + 32 * kk);
            Cq = __builtin_amdgcn_mfma_f32_16x16x32_f16(aq, wF[kk], Cq, 0, 0, 0);
            Cp = __builtin_amdgcn_mfma_f32_16x16x32_f16(ap, wF[kk], Cp, 0, 0, 0);
        }
        z1 = Cq[0]; P = Cp[0];
    }
    __syncthreads();   // protect ubuf before loop overwrites

    const float dt = 0.01f, hdt = 0.005f, dt6 = 0.01f / 6.f;
    const float dtdt6 = dt * dt6, hdt2 = hdt * hdt, dthdt = dt * hdt;

    float S1 = 0.f, S23 = 0.f, cn = 99.f;

    #pragma unroll 1
    for (int n = 0; n < NSTEPS; ++n) {
        // ======== phase A: u1, u2 -> Y1, Y2 ========
        float z2 = z1 + hdt * P;
        float e1 = __expf(2.f * z1), e2 = __expf(2.f * z2);
        float h1 = 1.f - 2.f / (e1 + 1.f), h2 = 1.f - 2.f / (e2 + 1.f);
        float u1 = (1.f - h1 * h1) * w2r, u2 = (1.f - h2 * h2) * w2r;
        if (quad == 0) {
            ubuf[0][comp] = (_Float16)u1;
            ubuf[1][comp] = (_Float16)u2;
        }
        __syncthreads();

        v4f C1a = {0.f,0.f,0.f,0.f}, C1b = {0.f,0.f,0.f,0.f};
        v4f C2a = {0.f,0.f,0.f,0.f}, C2b = {0.f,0.f,0.f,0.f};
        {
            const _Float16* b0 = &ubuf[0][0] + 8 * quad;
            const _Float16* b1p = &ubuf[1][0] + 8 * quad;
            #pragma unroll
            for (int kk = 0; kk < 8; kk += 2) {
                v8h a10 = *(const v8h*)(b0 + 32 * kk);
                v8h a20 = *(const v8h*)(b1p + 32 * kk);
                v8h a11 = *(const v8h*)(b0 + 32 * (kk + 1));
                v8h a21 = *(const v8h*)(b1p + 32 * (kk + 1));
                MFMA_AV(C1a, a10, wM[kk]);
                MFMA_AV(C2a, a20, wM[kk]);
                MFMA_AV(C1b, a11, wM[kk + 1]);
                MFMA_AV(C2b, a21, wM[kk + 1]);
            }
        }
        float Y1 = C1a[0] + C1b[0];
        float Y2 = C2a[0] + C2b[0];

        // ======== phase B: u3, u4 -> Y3, Y4 ========
        float z3 = z1 + hdt * P - hdt2 * Y1;
        float z4 = z1 + dt * P - dthdt * Y2;
        float e3 = __expf(2.f * z3), e4 = __expf(2.f * z4);
        float h3 = 1.f - 2.f / (e3 + 1.f), h4 = 1.f - 2.f / (e4 + 1.f);
        float u3 = (1.f - h3 * h3) * w2r, u4 = (1.f - h4 * h4) * w2r;
        if (quad == 0) {
            ubuf[2][comp] = (_Float16)u3;
            ubuf[3][comp] = (_Float16)u4;
        }
        __syncthreads();

        v4f C3a = {0.f,0.f,0.f,0.f}, C3b = {0.f,0.f,0.f,0.f};
        v4f C4a = {0.f,0.f,0.f,0.f}, C4b = {0.f,0.f,0.f,0.f};
        {
            const _Float16* b2 = &ubuf[2][0] + 8 * quad;
            const _Float16* b3 = &ubuf[3][0] + 8 * quad;
            #pragma unroll
            for (int kk = 0; kk < 8; kk += 2) {
                v8h a30 = *(const v8h*)(b2 + 32 * kk);
                v8h a40 = *(const v8h*)(b3 + 32 * kk);
                v8h a31 = *(const v8h*)(b2 + 32 * (kk + 1));
                v8h a41 = *(const v8h*)(b3 + 32 * (kk + 1));
                MFMA_AV(C3a, a30, wM[kk]);
                MFMA_AV(C4a, a40, wM[kk]);
                MFMA_AV(C3b, a31, wM[kk + 1]);
                MFMA_AV(C4b, a41, wM[kk + 1]);
            }
        }
        float Y3 = C3a[0] + C3b[0];
        float Y4 = C4a[0] + C4b[0];

        // ======== step update (z1 uses OLD P) ========
        z1 = z1 + dt * P - dtdt6 * (Y1 + Y2 + Y3);
        P  = P - dt6 * (Y1 + 2.f * Y2 + 2.f * Y3 + Y4);
        float sp = u1 + 2.f * u2 + 2.f * u3 + u4;
        float sq = u1 + u2 + u3;
        S1 += sp; S23 += cn * sp + sq; cn -= 1.f;
    }

    // ---- epilogue: p_T = p0 - dt6*W*S1; q_T = q0 + dt*100*p0 - dt*dt6*W*S23
    __syncthreads();   // all waves done reading ubuf before rewrite
    if (quad == 0) { ubuf[0][comp] = (_Float16)S1; ubuf[1][comp] = (_Float16)S23; }
    __syncthreads();
    v8h wBt[8];   // B-op: W[comp][32kk+8quad+j] (contiguous b128)
    #pragma unroll
    for (int kk = 0; kk < 8; ++kk)
        wBt[kk] = *(const v8h*)(wlds + comp * WS + 32 * kk + 8 * quad);
    v4f D1 = {0.f, 0.f, 0.f, 0.f}, D2 = {0.f, 0.f, 0.f, 0.f};
    {
        const _Float16* s1b = &ubuf[0][0] + 8 * quad;
        const _Float16* s2b = &ubuf[1][0] + 8 * quad;
        #pragma unroll
        for (int kk = 0; kk < 8; ++kk) {
            v8h a1 = *(const v8h*)(s1b + 32 * kk);
            v8h a2 = *(const v8h*)(s2b + 32 * kk);
            D1 = __builtin_amdgcn_mfma_f32_16x16x32_f16(a1, wBt[kk], D1, 0, 0, 0);
            D2 = __builtin_amdgcn_mfma_f32_16x16x32_f16(a2, wBt[kk], D2, 0, 0, 0);
        }
    }
    float pT = p0o - (0.01f / 6.f) * D1[0];
    float qT = q0o + 0.01f * (float)NSTEPS * p0o - dtdt6 * D2[0];

    if (quad == 0)
        ((float2*)(out + (size_t)blk * 512))[comp] = make_float2(qT, pT);
}

extern "C" void kernel_launch(void* const* d_in, const int* in_sizes, int n_in,
                              void* d_out, int out_size, void* d_ws, size_t ws_size,
                              hipStream_t stream) {
    const float* x0 = (const float*)d_in[0];
    const float* W1 = (const float*)d_in[1];
    const float* b1 = (const float*)d_in[2];
    const float* W2 = (const float*)d_in[3];
    // d_in[4] = b2: constant offset, no effect on the gradient/dynamics.
    float* out = (float*)d_out;
    hipLaunchKernelGGL(ham_kernel, dim3(256), dim3(1024), 0, stream,
                       x0, W1, b1, W2, out);
}

// Round 17
// 260.133 us; speedup vs baseline: 2.6418x; 1.0766x over previous
//
#include <hip/hip_runtime.h>
#include <stdint.h>

// HamiltonianFlow: x [256, 8, 32, 2] (q,p); H = 0.5*sum(p^2) + MLP(q).
// dq/dt = p, dp/dt = -W u(z), z = W^T q + b1, u = (1-tanh^2(z)).*W2.
// 100 RK4 steps, z-space iteration with M = W^T W (R15/R16-verified):
//   z2 = z1+hdt*P; z3 = z1+hdt*P-hdt^2*Y1; z4 = z1+dt*P-dt*hdt*Y2; Y_i = M u_i
//   z1' = z1+dt*P-dt*dt6*(Y1+Y2+Y3);  P' = P-dt6*(Y1+2Y2+2Y3+Y4)
// Phase A: u1,u2 -> {Y1,Y2}; phase B: u3,u4 -> {Y3,Y4}. 2 barriers/step.
//
// R17: PACK THE VECTOR PAIR INTO A's ROWS. R16 wasted 15/16 of each MFMA
// (A replicated over rows). Now A[row0]=u1, A[row1]=u2 (rows 2-15 junk):
// ONE 8-MFMA block yields D[0][s]=Y1[16w+s], D[1][s]=Y2[16w+s] -> halves
// MFMA issue (1033->516 cyc/SIMD/phase) and halves A-operand LDS reads.
// Results sit in quad-0 lanes (D rows 0,1 = C[0],C[1]); all lanes fetch
// their comp's Y via __shfl(Cs[r], s, 64) (in-wave ds_bpermute).
// A-read: addr = ubuf_base + (s==1 ? 256 : 0) + 32kk + 8quad; row-1 line
// aliases row-0's banks (256 f16 = 128 B) -> 2-way conflict = free (m136).
// Same packing: prologue (rows q0,p0 -> z1,P), epilogue (S1,S23).
// Reconstruction (R15-verified): sp=u1+2u2+2u3+u4, sq=u1+u2+u3;
//   S1=sum sp_n, S23=sum (99-n)sp_n+sq_n;
//   p_T = p0-dt6*W*S1, q_T = q0+dt*100*p0-dt*dt6*W*S23.
// M-build, AGPR-direct wM ("a" asm constraint), scr stride 20: R16-verified.
// Prologue aM gathers keep their 4-way quad conflicts (~15us, structural:
// conflict-free needs WS%8!=0 which breaks 16B row alignment - accepted).
// 16 waves (4/SIMD), wave w owns comps [16w,16w+16) (quads dup, comp=16w+s).
// FULL unroll on every reg-array access (R4: dynamic index => scratch).
// Numerics: f16 storage (W, M, u, S), fp32 MFMA accum + fp32 z1/P state.

typedef _Float16 v8h __attribute__((ext_vector_type(8)));
typedef _Float16 v4h __attribute__((ext_vector_type(4)));
typedef float v4f __attribute__((ext_vector_type(4)));

#define NSTEPS 100
#define WS 264   // padded f16 row stride (528 B: rows 16B-aligned)

// D(+=C) in VGPRs, A (packed-vector frag) in VGPRs, B (M-frag) from AGPRs.
#define MFMA_AV(C, A, B) \
    asm("v_mfma_f32_16x16x32_f16 %0, %1, %2, %0" : "+v"(C) : "v"(A), "a"(B))

__global__ __launch_bounds__(1024, 4)
void ham_kernel(const float* __restrict__ x0, const float* __restrict__ W1,
                const float* __restrict__ b1, const float* __restrict__ W2,
                float* __restrict__ out)
{
    __shared__ __align__(16) _Float16 wlds[256 * WS];   // 135168 B: W (f16)
    __shared__ __align__(16) float    mscr[16 * 320];   // 20480 B: M scratch
    __shared__ __align__(16) _Float16 ubuf[4][256];     // u1,u2,u3,u4 bcast

    const int t = threadIdx.x;
    const int w = t >> 6;          // wave 0..15: owns comps [16w, 16w+16)
    const int l = t & 63;
    const int quad = l >> 4;       // K-subgroup
    const int s = l & 15;          // owned column
    const int comp = 16 * w + s;
    const int blk = blockIdx.x;
    const int sel = (s == 1) ? 256 : 0;   // A-row select: row1 reads 2nd vector

    // ---- stage W1 -> LDS f16 (padded rows), coalesced ----
    #pragma unroll 1
    for (int k = t; k < 65536 / 4; k += 1024) {
        const int row = k >> 6, col4 = (k & 63) * 4;
        float4 v = ((const float4*)W1)[k];
        v4h h; h[0] = (_Float16)v.x; h[1] = (_Float16)v.y;
               h[2] = (_Float16)v.z; h[3] = (_Float16)v.w;
        *(v4h*)(wlds + row * WS + col4) = h;
    }
    __syncthreads();

    // ---- wF: own-column W^T frag (B-op): wF[kk][j] = W[32kk+8quad+j][comp]
    v8h wF[8];
    #pragma unroll
    for (int kk = 0; kk < 8; ++kk)
        #pragma unroll
        for (int j = 0; j < 8; ++j)
            wF[kk][j] = wlds[(32 * kk + 8 * quad + j) * WS + comp];

    // ---- build M = W^T W column-block frags wM (B-op: M[k][comp]) ----
    v8h wM[8];
    float* scr = mscr + w * 320;
    #pragma unroll
    for (int kb = 0; kb < 16; ++kb) {
        v8h aM[8];   // A[m=s][k=8quad+j] = W[32kk+8quad+j][16kb+s]
        #pragma unroll
        for (int kk = 0; kk < 8; ++kk)
            #pragma unroll
            for (int j = 0; j < 8; ++j)
                aM[kk][j] = wlds[(32 * kk + 8 * quad + j) * WS + 16 * kb + s];
        v4f D = {0.f, 0.f, 0.f, 0.f};
        #pragma unroll
        for (int kk = 0; kk < 8; ++kk)
            D = __builtin_amdgcn_mfma_f32_16x16x32_f16(aM[kk], wF[kk], D, 0, 0, 0);
        *(v4f*)(scr + s * 20 + 4 * quad) = D;
        asm volatile("s_waitcnt lgkmcnt(0)" ::: "memory");  // in-wave cross-lane
        if ((quad >> 1) == (kb & 1)) {
            #pragma unroll
            for (int j = 0; j < 8; ++j)
                wM[kb >> 1][j] = (_Float16)scr[s * 20 + 8 * (quad & 1) + j];
        }
        asm volatile("s_waitcnt lgkmcnt(0)" ::: "memory");
    }

    const float b1r = b1[comp];
    const float w2r = W2[comp];
    float2 qp = ((const float2*)(x0 + (size_t)blk * 512))[comp];
    const float q0o = qp.x, p0o = qp.y;

    // ---- prologue: rows {q0, p0} -> z1 = W^T q0 + b1, P = W^T p0 ----
    if (quad == 0) { ubuf[0][comp] = (_Float16)q0o; ubuf[1][comp] = (_Float16)p0o; }
    __syncthreads();
    float z1, P;
    {
        const _Float16* ab = &ubuf[0][0] + sel + 8 * quad;
        v4f Ca = {0.f,0.f,0.f,0.f}, Cb = {0.f,0.f,0.f,0.f};
        #pragma unroll
        for (int kk = 0; kk < 8; kk += 2) {
            v8h a0 = *(const v8h*)(ab + 32 * kk);
            v8h a1 = *(const v8h*)(ab + 32 * (kk + 1));
            Ca = __builtin_amdgcn_mfma_f32_16x16x32_f16(a0, wF[kk], Ca, 0, 0, 0);
            Cb = __builtin_amdgcn_mfma_f32_16x16x32_f16(a1, wF[kk + 1], Cb, 0, 0, 0);
        }
        v4f Cs = Ca + Cb;
        z1 = __shfl(Cs[0], s, 64) + b1r;
        P  = __shfl(Cs[1], s, 64);
    }
    __syncthreads();   // protect ubuf before loop overwrites

    const float dt = 0.01f, hdt = 0.005f, dt6 = 0.01f / 6.f;
    const float dtdt6 = dt * dt6, hdt2 = hdt * hdt, dthdt = dt * hdt;

    float S1 = 0.f, S23 = 0.f, cn = 99.f;

    #pragma unroll 1
    for (int n = 0; n < NSTEPS; ++n) {
        // ======== phase A: u1, u2 -> packed MFMA -> Y1, Y2 ========
        float z2 = z1 + hdt * P;
        float e1 = __expf(2.f * z1), e2 = __expf(2.f * z2);
        float h1 = 1.f - 2.f / (e1 + 1.f), h2 = 1.f - 2.f / (e2 + 1.f);
        float u1 = (1.f - h1 * h1) * w2r, u2 = (1.f - h2 * h2) * w2r;
        if (quad == 0) {
            ubuf[0][comp] = (_Float16)u1;
            ubuf[1][comp] = (_Float16)u2;
        }
        __syncthreads();

        float Y1, Y2;
        {
            const _Float16* ab = &ubuf[0][0] + sel + 8 * quad;
            v4f Ca = {0.f,0.f,0.f,0.f}, Cb = {0.f,0.f,0.f,0.f};
            #pragma unroll
            for (int kk = 0; kk < 8; kk += 2) {
                v8h a0 = *(const v8h*)(ab + 32 * kk);
                v8h a1 = *(const v8h*)(ab + 32 * (kk + 1));
                MFMA_AV(Ca, a0, wM[kk]);
                MFMA_AV(Cb, a1, wM[kk + 1]);
            }
            v4f Cs = Ca + Cb;
            Y1 = __shfl(Cs[0], s, 64);
            Y2 = __shfl(Cs[1], s, 64);
        }

        // ======== phase B: u3, u4 -> packed MFMA -> Y3, Y4 ========
        float z3 = z1 + hdt * P - hdt2 * Y1;
        float z4 = z1 + dt * P - dthdt * Y2;
        float e3 = __expf(2.f * z3), e4 = __expf(2.f * z4);
        float h3 = 1.f - 2.f / (e3 + 1.f), h4 = 1.f - 2.f / (e4 + 1.f);
        float u3 = (1.f - h3 * h3) * w2r, u4 = (1.f - h4 * h4) * w2r;
        if (quad == 0) {
            ubuf[2][comp] = (_Float16)u3;
            ubuf[3][comp] = (_Float16)u4;
        }
        __syncthreads();

        float Y3, Y4;
        {
            const _Float16* ab = &ubuf[2][0] + sel + 8 * quad;
            v4f Ca = {0.f,0.f,0.f,0.f}, Cb = {0.f,0.f,0.f,0.f};
            #pragma unroll
            for (int kk = 0; kk < 8; kk += 2) {
                v8h a0 = *(const v8h*)(ab + 32 * kk);
                v8h a1 = *(const v8h*)(ab + 32 * (kk + 1));
                MFMA_AV(Ca, a0, wM[kk]);
                MFMA_AV(Cb, a1, wM[kk + 1]);
            }
            v4f Cs = Ca + Cb;
            Y3 = __shfl(Cs[0], s, 64);
            Y4 = __shfl(Cs[1], s, 64);
        }

        // ======== step update (z1 uses OLD P) ========
        z1 = z1 + dt * P - dtdt6 * (Y1 + Y2 + Y3);
        P  = P - dt6 * (Y1 + 2.f * Y2 + 2.f * Y3 + Y4);
        float sp = u1 + 2.f * u2 + 2.f * u3 + u4;
        float sq = u1 + u2 + u3;
        S1 += sp; S23 += cn * sp + sq; cn -= 1.f;
    }

    // ---- epilogue: rows {S1, S23}: p_T = p0 - dt6*W*S1;
    //      q_T = q0 + dt*100*p0 - dt*dt6*W*S23 ----
    __syncthreads();   // all waves done reading ubuf before rewrite
    if (quad == 0) { ubuf[0][comp] = (_Float16)S1; ubuf[1][comp] = (_Float16)S23; }
    __syncthreads();
    v8h wBt[8];   // B-op: W[comp][32kk+8quad+j] (contiguous b128)
    #pragma unroll
    for (int kk = 0; kk < 8; ++kk)
        wBt[kk] = *(const v8h*)(wlds + comp * WS + 32 * kk + 8 * quad);
    float D1v, D2v;
    {
        const _Float16* ab = &ubuf[0][0] + sel + 8 * quad;
        v4f Ca = {0.f,0.f,0.f,0.f}, Cb = {0.f,0.f,0.f,0.f};
        #pragma unroll
        for (int kk = 0; kk < 8; kk += 2) {
            v8h a0 = *(const v8h*)(ab + 32 * kk);
            v8h a1 = *(const v8h*)(ab + 32 * (kk + 1));
            Ca = __builtin_amdgcn_mfma_f32_16x16x32_f16(a0, wBt[kk], Ca, 0, 0, 0);
            Cb = __builtin_amdgcn_mfma_f32_16x16x32_f16(a1, wBt[kk + 1], Cb, 0, 0, 0);
        }
        v4f Cs = Ca + Cb;
        D1v = __shfl(Cs[0], s, 64);
        D2v = __shfl(Cs[1], s, 64);
    }
    float pT = p0o - (0.01f / 6.f) * D1v;
    float qT = q0o + 0.01f * (float)NSTEPS * p0o - dtdt6 * D2v;

    if (quad == 0)
        ((float2*)(out + (size_t)blk * 512))[comp] = make_float2(qT, pT);
}

extern "C" void kernel_launch(void* const* d_in, const int* in_sizes, int n_in,
                              void* d_out, int out_size, void* d_ws, size_t ws_size,
                              hipStream_t stream) {
    const float* x0 = (const float*)d_in[0];
    const float* W1 = (const float*)d_in[1];
    const float* b1 = (const float*)d_in[2];
    const float* W2 = (const float*)d_in[3];
    // d_in[4] = b2: constant offset, no effect on the gradient/dynamics.
    float* out = (float*)d_out;
    hipLaunchKernelGGL(ham_kernel, dim3(256), dim3(1024), 0, stream,
                       x0, W1, b1, W2, out);
}

// Round 18
// 236.049 us; speedup vs baseline: 2.9113x; 1.1020x over previous
//
#include <hip/hip_runtime.h>
#include <stdint.h>

// HamiltonianFlow: x [256, 8, 32, 2] (q,p); H = 0.5*sum(p^2) + MLP(q).
// dq/dt = p, dp/dt = -W u(z), z = W^T q + b1, u = (1-tanh^2(z)).*W2.
// 100 RK4 steps, z-space iteration with M = W^T W (R15/R16/R17-verified):
//   z2 = z1+hdt*P; z3 = z1+hdt*P-hdt^2*Y1; z4 = z1+dt*P-dt*hdt*Y2; Y_i = M u_i
//   z1' = z1+dt*P-dt*dt6*(Y1+Y2+Y3);  P' = P-dt6*(Y1+2Y2+2Y3+Y4)
// Phase A: u1,u2 -> {Y1,Y2}; phase B: u3,u4 -> {Y3,Y4}. 2 barriers/step.
//
// R18 fixes R17's two LDS-pipe taxes (R17: +2.6e7 bank conflicts ~= 700
// cyc/phase, because vec2 at +512B hit the SAME banks as vec1's broadcast):
//  1. Vector-pair row stride 288 f16 (576 B == 64 mod 128): within one
//     ds_read_b128, vec1 lanes and vec2 lanes touch DISJOINT 16-bank
//     halves -> zero conflicts.
//  2. Replicated-row packing: A rows m%4==0 <- vec1, m%4==1 <- vec2 (lane
//     m=s reads row s; junk rows read vec1, benign). D row = 4*quad+reg =>
//     EVERY lane holds Y1=C[0], Y2=C[1] after the 8-MFMA block -> the two
//     __shfl bpermutes per phase are gone (were on the critical path).
// Same packing in prologue (z1=Cs[0]+b1, P=Cs[1]) and epilogue (D1,D2).
// M-build, AGPR-direct wM ("a" constraint), scr stride 20: R16/17-verified.
// (M-build aM gathers keep ~9.5e6 one-time conflicts: structural, accepted.)
// 16 waves (4/SIMD), wave w owns comps [16w,16w+16) (quads dup, comp=16w+s).
// Reconstruction (R15-verified): sp=u1+2u2+2u3+u4, sq=u1+u2+u3;
//   S1=sum sp_n, S23=sum (99-n)sp_n+sq_n;
//   p_T = p0-dt6*W*S1, q_T = q0+dt*100*p0-dt*dt6*W*S23.
// FULL unroll on every reg-array access (R4: dynamic index => scratch).
// Numerics: f16 storage (W, M, u, S), fp32 MFMA accum + fp32 z1/P state.

typedef _Float16 v8h __attribute__((ext_vector_type(8)));
typedef _Float16 v4h __attribute__((ext_vector_type(4)));
typedef float v4f __attribute__((ext_vector_type(4)));

#define NSTEPS 100
#define WS 264    // padded f16 row stride for W (528 B: rows 16B-aligned)
#define US 288    // ubuf row stride, f16 (576 B == 64 mod 128: bank-split)

// D(+=C) in VGPRs, A (packed-vector frag) in VGPRs, B (M-frag) from AGPRs.
#define MFMA_AV(C, A, B) \
    asm("v_mfma_f32_16x16x32_f16 %0, %1, %2, %0" : "+v"(C) : "v"(A), "a"(B))

__global__ __launch_bounds__(1024, 4)
void ham_kernel(const float* __restrict__ x0, const float* __restrict__ W1,
                const float* __restrict__ b1, const float* __restrict__ W2,
                float* __restrict__ out)
{
    __shared__ __align__(16)  _Float16 wlds[256 * WS];   // 135168 B: W (f16)
    __shared__ __align__(16)  float    mscr[16 * 320];   // 20480 B: M scratch
    __shared__ __align__(128) _Float16 ubuf[4 * US];     // 2304 B: 4 vec rows

    const int t = threadIdx.x;
    const int w = t >> 6;          // wave 0..15: owns comps [16w, 16w+16)
    const int l = t & 63;
    const int quad = l >> 4;       // K-subgroup
    const int s = l & 15;          // owned column / A-row
    const int comp = 16 * w + s;
    const int blk = blockIdx.x;
    const int sel = ((s & 3) == 1) ? US : 0;   // A-row m%4==1 -> 2nd vector

    // ---- stage W1 -> LDS f16 (padded rows), coalesced ----
    #pragma unroll 1
    for (int k = t; k < 65536 / 4; k += 1024) {
        const int row = k >> 6, col4 = (k & 63) * 4;
        float4 v = ((const float4*)W1)[k];
        v4h h; h[0] = (_Float16)v.x; h[1] = (_Float16)v.y;
               h[2] = (_Float16)v.z; h[3] = (_Float16)v.w;
        *(v4h*)(wlds + row * WS + col4) = h;
    }
    __syncthreads();

    // ---- wF: own-column W^T frag (B-op): wF[kk][j] = W[32kk+8quad+j][comp]
    v8h wF[8];
    #pragma unroll
    for (int kk = 0; kk < 8; ++kk)
        #pragma unroll
        for (int j = 0; j < 8; ++j)
            wF[kk][j] = wlds[(32 * kk + 8 * quad + j) * WS + comp];

    // ---- build M = W^T W column-block frags wM (B-op: M[k][comp]) ----
    v8h wM[8];
    float* scr = mscr + w * 320;
    #pragma unroll
    for (int kb = 0; kb < 16; ++kb) {
        v8h aM[8];   // A[m=s][k=8quad+j] = W[32kk+8quad+j][16kb+s]
        #pragma unroll
        for (int kk = 0; kk < 8; ++kk)
            #pragma unroll
            for (int j = 0; j < 8; ++j)
                aM[kk][j] = wlds[(32 * kk + 8 * quad + j) * WS + 16 * kb + s];
        v4f D = {0.f, 0.f, 0.f, 0.f};
        #pragma unroll
        for (int kk = 0; kk < 8; ++kk)
            D = __builtin_amdgcn_mfma_f32_16x16x32_f16(aM[kk], wF[kk], D, 0, 0, 0);
        *(v4f*)(scr + s * 20 + 4 * quad) = D;
        asm volatile("s_waitcnt lgkmcnt(0)" ::: "memory");  // in-wave cross-lane
        if ((quad >> 1) == (kb & 1)) {
            #pragma unroll
            for (int j = 0; j < 8; ++j)
                wM[kb >> 1][j] = (_Float16)scr[s * 20 + 8 * (quad & 1) + j];
        }
        asm volatile("s_waitcnt lgkmcnt(0)" ::: "memory");
    }

    const float b1r = b1[comp];
    const float w2r = W2[comp];
    float2 qp = ((const float2*)(x0 + (size_t)blk * 512))[comp];
    const float q0o = qp.x, p0o = qp.y;

    // ---- prologue: rows {q0, p0} -> z1 = W^T q0 + b1 (C[0]), P (C[1]) ----
    if (quad == 0) { ubuf[comp] = (_Float16)q0o; ubuf[US + comp] = (_Float16)p0o; }
    __syncthreads();
    float z1, P;
    {
        const _Float16* ab = ubuf + sel + 8 * quad;
        v4f Ca = {0.f,0.f,0.f,0.f}, Cb = {0.f,0.f,0.f,0.f};
        #pragma unroll
        for (int kk = 0; kk < 8; kk += 2) {
            v8h a0 = *(const v8h*)(ab + 32 * kk);
            v8h a1 = *(const v8h*)(ab + 32 * (kk + 1));
            Ca = __builtin_amdgcn_mfma_f32_16x16x32_f16(a0, wF[kk], Ca, 0, 0, 0);
            Cb = __builtin_amdgcn_mfma_f32_16x16x32_f16(a1, wF[kk + 1], Cb, 0, 0, 0);
        }
        v4f Cs = Ca + Cb;
        z1 = Cs[0] + b1r;
        P  = Cs[1];
    }
    __syncthreads();   // protect ubuf before loop overwrites

    const float dt = 0.01f, hdt = 0.005f, dt6 = 0.01f / 6.f;
    const float dtdt6 = dt * dt6, hdt2 = hdt * hdt, dthdt = dt * hdt;

    float S1 = 0.f, S23 = 0.f, cn = 99.f;

    #pragma unroll 1
    for (int n = 0; n < NSTEPS; ++n) {
        // ======== phase A: u1, u2 -> packed MFMA -> Y1, Y2 in-lane ========
        float z2 = z1 + hdt * P;
        float e1 = __expf(2.f * z1), e2 = __expf(2.f * z2);
        float h1 = 1.f - 2.f / (e1 + 1.f), h2 = 1.f - 2.f / (e2 + 1.f);
        float u1 = (1.f - h1 * h1) * w2r, u2 = (1.f - h2 * h2) * w2r;
        if (quad == 0) {
            ubuf[comp]      = (_Float16)u1;
            ubuf[US + comp] = (_Float16)u2;
        }
        __syncthreads();

        float Y1, Y2;
        {
            const _Float16* ab = ubuf + sel + 8 * quad;
            v4f Ca = {0.f,0.f,0.f,0.f}, Cb = {0.f,0.f,0.f,0.f};
            #pragma unroll
            for (int kk = 0; kk < 8; kk += 2) {
                v8h a0 = *(const v8h*)(ab + 32 * kk);
                v8h a1 = *(const v8h*)(ab + 32 * (kk + 1));
                MFMA_AV(Ca, a0, wM[kk]);
                MFMA_AV(Cb, a1, wM[kk + 1]);
            }
            v4f Cs = Ca + Cb;
            Y1 = Cs[0];   // D[4*quad+0][s]
            Y2 = Cs[1];   // D[4*quad+1][s]
        }

        // ======== phase B: u3, u4 -> packed MFMA -> Y3, Y4 in-lane ========
        float z3 = z1 + hdt * P - hdt2 * Y1;
        float z4 = z1 + dt * P - dthdt * Y2;
        float e3 = __expf(2.f * z3), e4 = __expf(2.f * z4);
        float h3 = 1.f - 2.f / (e3 + 1.f), h4 = 1.f - 2.f / (e4 + 1.f);
        float u3 = (1.f - h3 * h3) * w2r, u4 = (1.f - h4 * h4) * w2r;
        if (quad == 0) {
            ubuf[2 * US + comp] = (_Float16)u3;
            ubuf[3 * US + comp] = (_Float16)u4;
        }
        __syncthreads();

        float Y3, Y4;
        {
            const _Float16* ab = ubuf + 2 * US + sel + 8 * quad;
            v4f Ca = {0.f,0.f,0.f,0.f}, Cb = {0.f,0.f,0.f,0.f};
            #pragma unroll
            for (int kk = 0; kk < 8; kk += 2) {
                v8h a0 = *(const v8h*)(ab + 32 * kk);
                v8h a1 = *(const v8h*)(ab + 32 * (kk + 1));
                MFMA_AV(Ca, a0, wM[kk]);
                MFMA_AV(Cb, a1, wM[kk + 1]);
            }
            v4f Cs = Ca + Cb;
            Y3 = Cs[0];
            Y4 = Cs[1];
        }

        // ======== step update (z1 uses OLD P) ========
        z1 = z1 + dt * P - dtdt6 * (Y1 + Y2 + Y3);
        P  = P - dt6 * (Y1 + 2.f * Y2 + 2.f * Y3 + Y4);
        float sp = u1 + 2.f * u2 + 2.f * u3 + u4;
        float sq = u1 + u2 + u3;
        S1 += sp; S23 += cn * sp + sq; cn -= 1.f;
    }

    // ---- epilogue: rows {S1, S23}: p_T = p0 - dt6*W*S1;
    //      q_T = q0 + dt*100*p0 - dt*dt6*W*S23 ----
    __syncthreads();   // all waves done reading ubuf before rewrite
    if (quad == 0) { ubuf[comp] = (_Float16)S1; ubuf[US + comp] = (_Float16)S23; }
    __syncthreads();
    v8h wBt[8];   // B-op: W[comp][32kk+8quad+j] (contiguous b128)
    #pragma unroll
    for (int kk = 0; kk < 8; ++kk)
        wBt[kk] = *(const v8h*)(wlds + comp * WS + 32 * kk + 8 * quad);
    float D1v, D2v;
    {
        const _Float16* ab = ubuf + sel + 8 * quad;
        v4f Ca = {0.f,0.f,0.f,0.f}, Cb = {0.f,0.f,0.f,0.f};
        #pragma unroll
        for (int kk = 0; kk < 8; kk += 2) {
            v8h a0 = *(const v8h*)(ab + 32 * kk);
            v8h a1 = *(const v8h*)(ab + 32 * (kk + 1));
            Ca = __builtin_amdgcn_mfma_f32_16x16x32_f16(a0, wBt[kk], Ca, 0, 0, 0);
            Cb = __builtin_amdgcn_mfma_f32_16x16x32_f16(a1, wBt[kk + 1], Cb, 0, 0, 0);
        }
        v4f Cs = Ca + Cb;
        D1v = Cs[0];
        D2v = Cs[1];
    }
    float pT = p0o - (0.01f / 6.f) * D1v;
    float qT = q0o + 0.01f * (float)NSTEPS * p0o - dtdt6 * D2v;

    if (quad == 0)
        ((float2*)(out + (size_t)blk * 512))[comp] = make_float2(qT, pT);
}

extern "C" void kernel_launch(void* const* d_in, const int* in_sizes, int n_in,
                              void* d_out, int out_size, void* d_ws, size_t ws_size,
                              hipStream_t stream) {
    const float* x0 = (const float*)d_in[0];
    const float* W1 = (const float*)d_in[1];
    const float* b1 = (const float*)d_in[2];
    const float* W2 = (const float*)d_in[3];
    // d_in[4] = b2: constant offset, no effect on the gradient/dynamics.
    float* out = (float*)d_out;
    hipLaunchKernelGGL(ham_kernel, dim3(256), dim3(1024), 0, stream,
                       x0, W1, b1, W2, out);
}

// Round 19
// 227.855 us; speedup vs baseline: 3.0160x; 1.0360x over previous
//
#include <hip/hip_runtime.h>
#include <stdint.h>

// HamiltonianFlow: x [256, 8, 32, 2] (q,p); H = 0.5*sum(p^2) + MLP(q).
// dq/dt = p, dp/dt = -W u(z), z = W^T q + b1, u = (1-tanh^2(z)).*W2.
// 100 RK4 steps, z-space iteration with M = W^T W (R15-R18 verified):
//   z2 = z1+hdt*P; z3 = z1+hdt*P-hdt^2*Y1; z4 = z1+dt*P-dt*hdt*Y2; Y_i = M u_i
//   z1' = z1+dt*P-dt*dt6*(Y1+Y2+Y3);  P' = P-dt6*(Y1+2Y2+2Y3+Y4)
// Phase A: u1,u2 -> {Y1,Y2}; phase B: u3,u4 -> {Y3,Y4}. 2 barriers/step.
//
// R19: 8 WAVES x 2 TILES. R18's wall was the LDS pipe: 16 waves x 8
// ds_read_b128/phase = 128 instr/CU x ~12cyc ~= 1536 cyc/phase (vs MFMA 516,
// VALU ~400) -- every wave redundantly read the same 1 KB vector pair.
// A-frags are tile-independent: a wave owning TWO tiles reads the same
// 8 b128 but feeds 16 MFMAs -> 64 reads/CU/phase (~770 cyc). MFMA issue
// per SIMD unchanged (2 waves x 16 = 516 cyc). M-build gathers halve too
// (aM shared by both tile-MFMAs). Loop live-set: wM0/wM1 (64 regs, AGPR-
// direct "a" constraint) + ~30 scalars; wF dies after prologue.
// Wave w owns comps c0=32w+s (tile 2w), c1=32w+16+s (tile 2w+1); quads dup.
// Packed-pair A rows (R18-verified): rows m%4==0 <- vec1, m%4==1 <- vec2,
// ubuf row stride US=288 f16 (576B == 64 mod 128: vec2 lines on the opposite
// bank half -> conflict-free); result in-lane: Y_vec1 = Cs[0], Y_vec2 = Cs[1].
// Reconstruction (R15-verified): sp=u1+2u2+2u3+u4, sq=u1+u2+u3;
//   S1=sum sp_n, S23=sum (99-n)sp_n+sq_n;
//   p_T = p0-dt6*W*S1, q_T = q0+dt*100*p0-dt*dt6*W*S23.
// FULL unroll on every reg-array access (R4: dynamic index => scratch).
// Numerics: f16 storage (W, M, u, S), fp32 MFMA accum + fp32 z1/P state.

typedef _Float16 v8h __attribute__((ext_vector_type(8)));
typedef _Float16 v4h __attribute__((ext_vector_type(4)));
typedef float v4f __attribute__((ext_vector_type(4)));

#define NSTEPS 100
#define WS 264    // padded f16 row stride for W (528 B: rows 16B-aligned)
#define US 288    // ubuf row stride, f16 (576 B == 64 mod 128: bank-split)

// D(+=C) in VGPRs, A (packed-vector frag) in VGPRs, B (M-frag) from AGPRs.
#define MFMA_AV(C, A, B) \
    asm("v_mfma_f32_16x16x32_f16 %0, %1, %2, %0" : "+v"(C) : "v"(A), "a"(B))

__global__ __launch_bounds__(512, 2)
void ham_kernel(const float* __restrict__ x0, const float* __restrict__ W1,
                const float* __restrict__ b1, const float* __restrict__ W2,
                float* __restrict__ out)
{
    __shared__ __align__(16)  _Float16 wlds[256 * WS];   // 135168 B: W (f16)
    __shared__ __align__(16)  float    mscr[8 * 640];    // 20480 B: M scratch
    __shared__ __align__(128) _Float16 ubuf[4 * US];     // 2304 B: 4 vec rows

    const int t = threadIdx.x;
    const int w = t >> 6;          // wave 0..7: owns tiles {2w, 2w+1}
    const int l = t & 63;
    const int quad = l >> 4;       // K-subgroup
    const int s = l & 15;          // owned column / A-row
    const int c0 = 32 * w + s;          // comp, tile 2w
    const int c1 = 32 * w + 16 + s;     // comp, tile 2w+1
    const int blk = blockIdx.x;
    const int sel = ((s & 3) == 1) ? US : 0;   // A-row m%4==1 -> 2nd vector

    // ---- stage W1 -> LDS f16 (padded rows), coalesced ----
    #pragma unroll 1
    for (int k = t; k < 65536 / 4; k += 512) {
        const int row = k >> 6, col4 = (k & 63) * 4;
        float4 v = ((const float4*)W1)[k];
        v4h h; h[0] = (_Float16)v.x; h[1] = (_Float16)v.y;
               h[2] = (_Float16)v.z; h[3] = (_Float16)v.w;
        *(v4h*)(wlds + row * WS + col4) = h;
    }
    __syncthreads();

    // ---- wF: own-column W^T frags (B-op), both tiles ----
    v8h wF0[8], wF1[8];
    #pragma unroll
    for (int kk = 0; kk < 8; ++kk)
        #pragma unroll
        for (int j = 0; j < 8; ++j) {
            wF0[kk][j] = wlds[(32 * kk + 8 * quad + j) * WS + c0];
            wF1[kk][j] = wlds[(32 * kk + 8 * quad + j) * WS + c1];
        }

    // ---- build M = W^T W column-block frags wM0/wM1 (B-op: M[k][c]) ----
    v8h wM0[8], wM1[8];
    float* scr0 = mscr + w * 640;
    float* scr1 = scr0 + 320;
    #pragma unroll
    for (int kb = 0; kb < 16; ++kb) {
        v8h aM[8];   // A[m=s][k=8quad+j] = W[32kk+8quad+j][16kb+s]  (shared)
        #pragma unroll
        for (int kk = 0; kk < 8; ++kk)
            #pragma unroll
            for (int j = 0; j < 8; ++j)
                aM[kk][j] = wlds[(32 * kk + 8 * quad + j) * WS + 16 * kb + s];
        v4f D0 = {0.f,0.f,0.f,0.f}, D1 = {0.f,0.f,0.f,0.f};
        #pragma unroll
        for (int kk = 0; kk < 8; ++kk) {
            D0 = __builtin_amdgcn_mfma_f32_16x16x32_f16(aM[kk], wF0[kk], D0, 0, 0, 0);
            D1 = __builtin_amdgcn_mfma_f32_16x16x32_f16(aM[kk], wF1[kk], D1, 0, 0, 0);
        }
        *(v4f*)(scr0 + s * 20 + 4 * quad) = D0;
        *(v4f*)(scr1 + s * 20 + 4 * quad) = D1;
        asm volatile("s_waitcnt lgkmcnt(0)" ::: "memory");  // in-wave cross-lane
        if ((quad >> 1) == (kb & 1)) {
            #pragma unroll
            for (int j = 0; j < 8; ++j) {
                wM0[kb >> 1][j] = (_Float16)scr0[s * 20 + 8 * (quad & 1) + j];
                wM1[kb >> 1][j] = (_Float16)scr1[s * 20 + 8 * (quad & 1) + j];
            }
        }
        asm volatile("s_waitcnt lgkmcnt(0)" ::: "memory");
    }

    const float b1r0 = b1[c0], b1r1 = b1[c1];
    const float w2r0 = W2[c0], w2r1 = W2[c1];
    float2 qp0 = ((const float2*)(x0 + (size_t)blk * 512))[c0];
    float2 qp1 = ((const float2*)(x0 + (size_t)blk * 512))[c1];
    const float q0o0 = qp0.x, p0o0 = qp0.y;
    const float q0o1 = qp1.x, p0o1 = qp1.y;

    // ---- prologue: rows {q0, p0} -> z1 = W^T q0 + b1 (Cs[0]), P (Cs[1]) ----
    if (quad == 0) {
        ubuf[c0] = (_Float16)q0o0;  ubuf[c1] = (_Float16)q0o1;
        ubuf[US + c0] = (_Float16)p0o0;  ubuf[US + c1] = (_Float16)p0o1;
    }
    __syncthreads();
    float z10, P0, z11, P1;
    {
        const _Float16* ab = ubuf + sel + 8 * quad;
        v4f C0a = {0.f,0.f,0.f,0.f}, C0b = {0.f,0.f,0.f,0.f};
        v4f C1a = {0.f,0.f,0.f,0.f}, C1b = {0.f,0.f,0.f,0.f};
        #pragma unroll
        for (int kk = 0; kk < 8; kk += 2) {
            v8h a0 = *(const v8h*)(ab + 32 * kk);
            v8h a1 = *(const v8h*)(ab + 32 * (kk + 1));
            C0a = __builtin_amdgcn_mfma_f32_16x16x32_f16(a0, wF0[kk], C0a, 0, 0, 0);
            C1a = __builtin_amdgcn_mfma_f32_16x16x32_f16(a0, wF1[kk], C1a, 0, 0, 0);
            C0b = __builtin_amdgcn_mfma_f32_16x16x32_f16(a1, wF0[kk + 1], C0b, 0, 0, 0);
            C1b = __builtin_amdgcn_mfma_f32_16x16x32_f16(a1, wF1[kk + 1], C1b, 0, 0, 0);
        }
        v4f C0s = C0a + C0b, C1s = C1a + C1b;
        z10 = C0s[0] + b1r0;  P0 = C0s[1];
        z11 = C1s[0] + b1r1;  P1 = C1s[1];
    }
    __syncthreads();   // protect ubuf before loop overwrites

    const float dt = 0.01f, hdt = 0.005f, dt6 = 0.01f / 6.f;
    const float dtdt6 = dt * dt6, hdt2 = hdt * hdt, dthdt = dt * hdt;

    float S10 = 0.f, S230 = 0.f, S11 = 0.f, S231 = 0.f, cn = 99.f;

    #pragma unroll 1
    for (int n = 0; n < NSTEPS; ++n) {
        // ======== phase A: u1, u2 (both comps) -> packed MFMA -> Y1, Y2 ====
        float z20 = z10 + hdt * P0, z21 = z11 + hdt * P1;
        float e10 = __expf(2.f * z10), e20 = __expf(2.f * z20);
        float e11 = __expf(2.f * z11), e21 = __expf(2.f * z21);
        float h10 = 1.f - 2.f / (e10 + 1.f), h20 = 1.f - 2.f / (e20 + 1.f);
        float h11 = 1.f - 2.f / (e11 + 1.f), h21 = 1.f - 2.f / (e21 + 1.f);
        float u10 = (1.f - h10 * h10) * w2r0, u20 = (1.f - h20 * h20) * w2r0;
        float u11 = (1.f - h11 * h11) * w2r1, u21 = (1.f - h21 * h21) * w2r1;
        if (quad == 0) {
            ubuf[c0] = (_Float16)u10;       ubuf[c1] = (_Float16)u11;
            ubuf[US + c0] = (_Float16)u20;  ubuf[US + c1] = (_Float16)u21;
        }
        __syncthreads();

        float Y10, Y20, Y11, Y21;
        {
            const _Float16* ab = ubuf + sel + 8 * quad;
            v4f C0a = {0.f,0.f,0.f,0.f}, C0b = {0.f,0.f,0.f,0.f};
            v4f C1a = {0.f,0.f,0.f,0.f}, C1b = {0.f,0.f,0.f,0.f};
            #pragma unroll
            for (int kk = 0; kk < 8; kk += 2) {
                v8h a0 = *(const v8h*)(ab + 32 * kk);
                v8h a1 = *(const v8h*)(ab + 32 * (kk + 1));
                MFMA_AV(C0a, a0, wM0[kk]);
                MFMA_AV(C1a, a0, wM1[kk]);
                MFMA_AV(C0b, a1, wM0[kk + 1]);
                MFMA_AV(C1b, a1, wM1[kk + 1]);
            }
            v4f C0s = C0a + C0b, C1s = C1a + C1b;
            Y10 = C0s[0];  Y20 = C0s[1];
            Y11 = C1s[0];  Y21 = C1s[1];
        }

        // ======== phase B: u3, u4 -> packed MFMA -> Y3, Y4 ========
        float z30 = z10 + hdt * P0 - hdt2 * Y10;
        float z40 = z10 + dt * P0 - dthdt * Y20;
        float z31 = z11 + hdt * P1 - hdt2 * Y11;
        float z41 = z11 + dt * P1 - dthdt * Y21;
        float e30 = __expf(2.f * z30), e40 = __expf(2.f * z40);
        float e31 = __expf(2.f * z31), e41 = __expf(2.f * z41);
        float h30 = 1.f - 2.f / (e30 + 1.f), h40 = 1.f - 2.f / (e40 + 1.f);
        float h31 = 1.f - 2.f / (e31 + 1.f), h41 = 1.f - 2.f / (e41 + 1.f);
        float u30 = (1.f - h30 * h30) * w2r0, u40 = (1.f - h40 * h40) * w2r0;
        float u31 = (1.f - h31 * h31) * w2r1, u41 = (1.f - h41 * h41) * w2r1;
        if (quad == 0) {
            ubuf[2 * US + c0] = (_Float16)u30;  ubuf[2 * US + c1] = (_Float16)u31;
            ubuf[3 * US + c0] = (_Float16)u40;  ubuf[3 * US + c1] = (_Float16)u41;
        }
        __syncthreads();

        float Y30, Y40, Y31, Y41;
        {
            const _Float16* ab = ubuf + 2 * US + sel + 8 * quad;
            v4f C0a = {0.f,0.f,0.f,0.f}, C0b = {0.f,0.f,0.f,0.f};
            v4f C1a = {0.f,0.f,0.f,0.f}, C1b = {0.f,0.f,0.f,0.f};
            #pragma unroll
            for (int kk = 0; kk < 8; kk += 2) {
                v8h a0 = *(const v8h*)(ab + 32 * kk);
                v8h a1 = *(const v8h*)(ab + 32 * (kk + 1));
                MFMA_AV(C0a, a0, wM0[kk]);
                MFMA_AV(C1a, a0, wM1[kk]);
                MFMA_AV(C0b, a1, wM0[kk + 1]);
                MFMA_AV(C1b, a1, wM1[kk + 1]);
            }
            v4f C0s = C0a + C0b, C1s = C1a + C1b;
            Y30 = C0s[0];  Y40 = C0s[1];
            Y31 = C1s[0];  Y41 = C1s[1];
        }

        // ======== step update (z1 uses OLD P), both comps ========
        z10 = z10 + dt * P0 - dtdt6 * (Y10 + Y20 + Y30);
        P0  = P0 - dt6 * (Y10 + 2.f * Y20 + 2.f * Y30 + Y40);
        z11 = z11 + dt * P1 - dtdt6 * (Y11 + Y21 + Y31);
        P1  = P1 - dt6 * (Y11 + 2.f * Y21 + 2.f * Y31 + Y41);
        float sp0 = u10 + 2.f * u20 + 2.f * u30 + u40;
        float sq0 = u10 + u20 + u30;
        float sp1 = u11 + 2.f * u21 + 2.f * u31 + u41;
        float sq1 = u11 + u21 + u31;
        S10 += sp0; S230 += cn * sp0 + sq0;
        S11 += sp1; S231 += cn * sp1 + sq1;
        cn -= 1.f;
    }

    // ---- epilogue: rows {S1, S23}: p_T = p0 - dt6*W*S1;
    //      q_T = q0 + dt*100*p0 - dt*dt6*W*S23 ----
    __syncthreads();   // all waves done reading ubuf before rewrite
    if (quad == 0) {
        ubuf[c0] = (_Float16)S10;       ubuf[c1] = (_Float16)S11;
        ubuf[US + c0] = (_Float16)S230; ubuf[US + c1] = (_Float16)S231;
    }
    __syncthreads();
    v8h wBt0[8], wBt1[8];   // B-op: W[c][32kk+8quad+j] (contiguous b128)
    #pragma unroll
    for (int kk = 0; kk < 8; ++kk) {
        wBt0[kk] = *(const v8h*)(wlds + c0 * WS + 32 * kk + 8 * quad);
        wBt1[kk] = *(const v8h*)(wlds + c1 * WS + 32 * kk + 8 * quad);
    }
    float D10, D20, D11, D21;
    {
        const _Float16* ab = ubuf + sel + 8 * quad;
        v4f C0a = {0.f,0.f,0.f,0.f}, C0b = {0.f,0.f,0.f,0.f};
        v4f C1a = {0.f,0.f,0.f,0.f}, C1b = {0.f,0.f,0.f,0.f};
        #pragma unroll
        for (int kk = 0; kk < 8; kk += 2) {
            v8h a0 = *(const v8h*)(ab + 32 * kk);
            v8h a1 = *(const v8h*)(ab + 32 * (kk + 1));
            C0a = __builtin_amdgcn_mfma_f32_16x16x32_f16(a0, wBt0[kk], C0a, 0, 0, 0);
            C1a = __builtin_amdgcn_mfma_f32_16x16x32_f16(a0, wBt1[kk], C1a, 0, 0, 0);
            C0b = __builtin_amdgcn_mfma_f32_16x16x32_f16(a1, wBt0[kk + 1], C0b, 0, 0, 0);
            C1b = __builtin_amdgcn_mfma_f32_16x16x32_f16(a1, wBt1[kk + 1], C1b, 0, 0, 0);
        }
        v4f C0s = C0a + C0b, C1s = C1a + C1b;
        D10 = C0s[0];  D20 = C0s[1];
        D11 = C1s[0];  D21 = C1s[1];
    }
    float pT0 = p0o0 - dt6 * D10;
    float qT0 = q0o0 + dt * (float)NSTEPS * p0o0 - dtdt6 * D20;
    float pT1 = p0o1 - dt6 * D11;
    float qT1 = q0o1 + dt * (float)NSTEPS * p0o1 - dtdt6 * D21;

    if (quad == 0) {
        ((float2*)(out + (size_t)blk * 512))[c0] = make_float2(qT0, pT0);
        ((float2*)(out + (size_t)blk * 512))[c1] = make_float2(qT1, pT1);
    }
}

extern "C" void kernel_launch(void* const* d_in, const int* in_sizes, int n_in,
                              void* d_out, int out_size, void* d_ws, size_t ws_size,
                              hipStream_t stream) {
    const float* x0 = (const float*)d_in[0];
    const float* W1 = (const float*)d_in[1];
    const float* b1 = (const float*)d_in[2];
    const float* W2 = (const float*)d_in[3];
    // d_in[4] = b2: constant offset, no effect on the gradient/dynamics.
    float* out = (float*)d_out;
    hipLaunchKernelGGL(ham_kernel, dim3(256), dim3(512), 0, stream,
                       x0, W1, b1, W2, out);
}